// Round 5
// baseline (243.881 us; speedup 1.0000x reference)
//
#include <hip/hip_runtime.h>
#include <hip/hip_bf16.h>
#include <math.h>

typedef unsigned short u16;

#define BATCH  16384
#define HID    512
#define KDIM   1024   // INPUT + HIDDEN
#define BM     128    // batch rows per block
#define BNG    64     // per-gate cols per block (x4 gates); 4 waves x 16 cols
#define CHUNK  128    // K per LDS buffer
#define NCHUNK 8

typedef __bf16 bf16x8 __attribute__((ext_vector_type(8)));
typedef float  floatx4 __attribute__((ext_vector_type(4)));

__device__ __forceinline__ void async_copy16(const void* g, void* l) {
  __builtin_amdgcn_global_load_lds(
      (const __attribute__((address_space(1))) void*)g,
      (__attribute__((address_space(3))) void*)l, 16, 0, 0);
}

__device__ __forceinline__ float fast_sigmoid(float x) {
  return 1.0f / (1.0f + __expf(-x));
}
__device__ __forceinline__ float fast_tanh(float x) {
  float e = __expf(-2.0f * fabsf(x));
  float t = (1.0f - e) / (1.0f + e);
  return x >= 0.0f ? t : -t;
}
__device__ __forceinline__ u16 f2bf(float f) {
  return __builtin_bit_cast(u16, __float2bfloat16(f));
}

// ---------- pre-pass: fp32 -> bf16 packing (identical to R4, verified) ----
// Xb: row-major [BATCH][KDIM], X[b] = [prev_h[b] | input_[b]].
// Wf: MFMA-fragment-major: elem (gate g, per-gate col n, k) at
//   (((g*32 + n/16)*32 + k/32)*64 + ((k>>3)&3)*16 + (n&15))*8 + (k&7)
//   -> one coalesced 16B/lane load per (tile,kstep32) fragment.
__global__ __launch_bounds__(256) void pack_kernel(
    const float* __restrict__ input_, const float* __restrict__ prev_h,
    const float* __restrict__ Wi, const float* __restrict__ Wf_,
    const float* __restrict__ Wo, const float* __restrict__ Wg,
    u16* __restrict__ Xb, u16* __restrict__ Wf) {
  int blk = blockIdx.x;
  int k = threadIdx.x * 4;
  if (blk < BATCH) {
    const float* src = (k < HID) ? (prev_h + (size_t)blk * HID + k)
                                 : (input_ + (size_t)blk * HID + (k - HID));
    float4 v = *(const float4*)src;
    ushort4 o;
    o.x = f2bf(v.x); o.y = f2bf(v.y); o.z = f2bf(v.z); o.w = f2bf(v.w);
    *(ushort4*)(Xb + (size_t)blk * KDIM + k) = o;
  } else {
    int grow = blk - BATCH;               // 0..2047, order [Wi|Wf|Wo|Wg]
    int g = grow >> 9;
    int n = grow & (HID - 1);
    const float* s = g == 0 ? Wi : g == 1 ? Wf_ : g == 2 ? Wo : Wg;
    float4 v = *(const float4*)(s + (size_t)n * KDIM + k);
    ushort4 o;
    o.x = f2bf(v.x); o.y = f2bf(v.y); o.z = f2bf(v.z); o.w = f2bf(v.w);
    size_t d = ((size_t)((g * 32 + (n >> 4)) * 32 + (k >> 5)) * 64 +
                ((k >> 3) & 3) * 16 + (n & 15)) * 8 + (k & 7);
    *(ushort4*)(Wf + d) = o;
  }
}

// ---------- main fused GEMM + LSTM epilogue ----------
// R4 lesson: barrier's vmcnt(0) drains ALL vmem (single counter) -> B reg
// loads don't pipeline across barriers, and 1 block/CU meant every barrier
// stalled the whole CU. This version: K chunked at 128 -> ONE barrier per
// chunk (8 total), 128 MFMA/wave between barriers; fill(c+1) issued at
// window start has the whole compute window to land (drain residual ~0);
// B loads are issued and consumed inside the window. 256-thread blocks +
// 64KB LDS + ~250 regs -> 2 blocks/CU for cross-block overlap at barriers.
// LDS swizzle = R2's measured-zero-conflict scheme per 64-elem half-row.
__global__ __launch_bounds__(256, 2) void lstm_gemm_kernel(
    const u16* __restrict__ Xb, const u16* __restrict__ Wf,
    const float* __restrict__ Bi, const float* __restrict__ Bf,
    const float* __restrict__ Bo, const float* __restrict__ Bg,
    const float* __restrict__ prevC, float* __restrict__ out) {
  __shared__ u16 lds[2][16384];   // per buf: 2 k-halves x 128 rows x 64 elems

  const int tid = threadIdx.x;
  const int wave = tid >> 6, lane = tid & 63;
  const int lrow = lane & 15, lquad = lane >> 4;
  const int m_block = blockIdx.x * BM;
  const int ntg = blockIdx.y * 4 + wave;   // per-gate 16-col tile id, 0..31

  // A staging: 32 instrs per 32KB chunk fill, 8 per wave. Instr li (0..31):
  // half=li>>4 (k 0/64), j=li&15 -> rows j*8+(lane>>3), swizzled 16B chunk.
  const int swz = ((lane & 7) ^ ((lane >> 3) & 7)) * 8;
  const u16* gp[8];
  int lp[8];
#pragma unroll
  for (int i = 0; i < 8; ++i) {
    int li = wave * 8 + i;
    int half = li >> 4, j = li & 15;
    gp[i] = Xb + (size_t)(m_block + j * 8 + (lane >> 3)) * KDIM + half * 64 + swz;
    lp[i] = half * 8192 + j * 512;
  }

  floatx4 acc[4][8];   // [gate][m-tile]
#pragma unroll
  for (int g = 0; g < 4; ++g)
#pragma unroll
    for (int mt = 0; mt < 8; ++mt)
      acc[g][mt] = (floatx4){0.f, 0.f, 0.f, 0.f};

  auto fill = [&](int buf, int c) {
#pragma unroll
    for (int i = 0; i < 8; ++i)
      async_copy16(gp[i] + c * CHUNK, &lds[0][0] + buf * 16384 + lp[i]);
  };

  auto compute = [&](int buf, int c) {
#pragma unroll
    for (int half = 0; half < 2; ++half) {
      const int t = c * 4 + half * 2;          // kstep32 index base
      bf16x8 b[2][4];
#pragma unroll
      for (int kk = 0; kk < 2; ++kk)
#pragma unroll
        for (int g = 0; g < 4; ++g)
          b[kk][g] = *(const bf16x8*)(
              Wf + (((size_t)(g * 32 + ntg) * 32 + t + kk) << 9) + lane * 8);
      const u16* LA = &lds[buf][half * 8192];
#pragma unroll
      for (int kk = 0; kk < 2; ++kk) {
#pragma unroll
        for (int mt = 0; mt < 8; ++mt) {
          bf16x8 a = *(const bf16x8*)
              &LA[(mt * 16 + lrow) * 64 + (((kk * 4 + lquad) ^ (lrow & 7)) * 8)];
#pragma unroll
          for (int g = 0; g < 4; ++g)
            acc[g][mt] = __builtin_amdgcn_mfma_f32_16x16x32_bf16(
                a, b[kk][g], acc[g][mt], 0, 0, 0);
        }
      }
    }
  };

  fill(0, 0);
  for (int c = 0; c < NCHUNK; ++c) {
    __syncthreads();                    // fill(c) landed; prev readers done
    if (c + 1 < NCHUNK) fill((c + 1) & 1, c + 1);
    compute(c & 1, c);
  }

  // Epilogue. C layout (verified): col=lane&15, row=lquad*4+reg.
  const int j = ntg * 16 + lrow;        // 0..511
  const float vbi = Bi[j], vbf = Bf[j], vbo = Bo[j], vbg = Bg[j];
  float* outH = out;
  float* outC = out + (size_t)BATCH * HID;
#pragma unroll
  for (int mt = 0; mt < 8; ++mt) {
    int rowb = m_block + mt * 16 + lquad * 4;
#pragma unroll
    for (int r = 0; r < 4; ++r) {
      int row = rowb + r;
      float gi = fast_sigmoid(acc[0][mt][r] + vbi);
      float gf = fast_sigmoid(acc[1][mt][r] + vbf);
      float go = fast_sigmoid(acc[2][mt][r] + vbo);
      float gg = fast_tanh(acc[3][mt][r] + vbg);
      float c = gf * prevC[row * HID + j] + gi * gg;
      float h = fast_tanh(c) * go;
      outH[row * HID + j] = h;
      outC[row * HID + j] = c;
    }
  }
}

// ---------- slow fallback if ws too small (correctness insurance) ----------
__global__ void lstm_fallback_kernel(
    const float* __restrict__ input_, const float* __restrict__ prev_h,
    const float* __restrict__ prevC,
    const float* __restrict__ Wi, const float* __restrict__ Bi,
    const float* __restrict__ Wf, const float* __restrict__ Bf,
    const float* __restrict__ Wo, const float* __restrict__ Bo,
    const float* __restrict__ Wg, const float* __restrict__ Bg,
    float* __restrict__ out) {
  int idx = blockIdx.x * blockDim.x + threadIdx.x;
  int b = idx / HID, j = idx % HID;
  if (b >= BATCH) return;
  float si = 0.f, sf = 0.f, so = 0.f, sg = 0.f;
  for (int k = 0; k < KDIM; ++k) {
    float x = (k < HID) ? prev_h[b * HID + k] : input_[b * HID + (k - HID)];
    si += x * Wi[j * KDIM + k];
    sf += x * Wf[j * KDIM + k];
    so += x * Wo[j * KDIM + k];
    sg += x * Wg[j * KDIM + k];
  }
  float gi = fast_sigmoid(si + Bi[j]);
  float gf = fast_sigmoid(sf + Bf[j]);
  float go = fast_sigmoid(so + Bo[j]);
  float gg = fast_tanh(sg + Bg[j]);
  float c = gf * prevC[b * HID + j] + gi * gg;
  out[b * HID + j] = fast_tanh(c) * go;
  out[(size_t)BATCH * HID + b * HID + j] = c;
}

extern "C" void kernel_launch(void* const* d_in, const int* in_sizes, int n_in,
                              void* d_out, int out_size, void* d_ws, size_t ws_size,
                              hipStream_t stream) {
  const float* input_ = (const float*)d_in[0];
  const float* prev_h = (const float*)d_in[1];
  const float* prev_c = (const float*)d_in[2];
  const float* W_i = (const float*)d_in[3];
  const float* b_i = (const float*)d_in[4];
  const float* W_f = (const float*)d_in[5];
  const float* b_f = (const float*)d_in[6];
  const float* W_g = (const float*)d_in[7];
  const float* b_g = (const float*)d_in[8];
  const float* W_o = (const float*)d_in[9];
  const float* b_o = (const float*)d_in[10];
  float* out = (float*)d_out;

  const size_t ws_needed =
      (size_t)BATCH * KDIM * sizeof(u16) + (size_t)4 * HID * KDIM * sizeof(u16);

  if (ws_size < ws_needed) {
    int total = BATCH * HID;
    lstm_fallback_kernel<<<(total + 255) / 256, 256, 0, stream>>>(
        input_, prev_h, prev_c, W_i, b_i, W_f, b_f, W_o, b_o, W_g, b_g, out);
    return;
  }

  u16* Xb = (u16*)d_ws;                       // 16384 x 1024 bf16 = 33.5 MB
  u16* Wfm = Xb + (size_t)BATCH * KDIM;       // fragment-major W, 4 MB

  pack_kernel<<<BATCH + 4 * HID, 256, 0, stream>>>(input_, prev_h,
                                                   W_i, W_f, W_o, W_g, Xb, Wfm);

  dim3 grid(BATCH / BM, HID / BNG);           // 128 x 8 = 1024 blocks
  lstm_gemm_kernel<<<grid, 256, 0, stream>>>(Xb, Wfm, b_i, b_f, b_o, b_g,
                                             prev_c, out);
}